// Round 5
// baseline (892.887 us; speedup 1.0000x reference)
//
#include <hip/hip_runtime.h>
#include <cmath>

using f32x4 = __attribute__((ext_vector_type(4))) float;
using f16x8 = __attribute__((ext_vector_type(8))) _Float16;

#define SCL_H  256.0f
#define INV_HH (1.0f/65536.0f)

// ---------------- workspace layout (float units) ----------------
#define WS_ZH   ((size_t)0)
#define WS_ZL   ((size_t)4194304)
#define WS_EH   ((size_t)8388608)
#define WS_EL   ((size_t)12582912)
#define WS_Z2T  ((size_t)16777216)
#define WS_Z2G  ((size_t)16785408)
#define WS_E2T  ((size_t)16793600)
#define WS_E2G  ((size_t)16801792)
#define WS_PM   ((size_t)16809984)
#define WS_PZ   ((size_t)17334272)
#define WS_PS1  ((size_t)17858560)
#define WS_PDM  ((size_t)18382848)
#define WS_PDT  ((size_t)18907136)
#define WS_PDG  ((size_t)19431424)
#define WS_PIX  ((size_t)19955712)
#define WS_PSC  ((size_t)20480000)
#define WS_LSE  ((size_t)21004288)
#define WS_IDX  ((size_t)21012480)
#define WS_RENT ((size_t)21020672)
#define WS_RDT  ((size_t)21028864)
#define WS_RDG  ((size_t)21037056)
#define WS_GVQ  ((size_t)21045248)
#define WS_AVG4 ((size_t)21053440)
#define WS_QM   ((size_t)21118976)
#define WS_STORE_END ((size_t)54673408)

// ---------------- output layout (floats) ----------------
#define O_VQ  ((size_t)8388608)
#define O_CM  ((size_t)8388609)
#define O_ENT ((size_t)8388610)
#define O_TD  ((size_t)8388611)
#define O_GD  ((size_t)8388612)
#define O_ZT  ((size_t)8388613)
#define O_ZG  ((size_t)12582917)
#define O_IX  ((size_t)16777221)

__device__ __forceinline__ size_t tiled_off(int row, int chunk) {
    // chunk = k/8 in [0,128). layout: [rowblk][kt][slot][row&127][8]
    return (((size_t)(row >> 7) * 32 + (chunk >> 2)) * 4 + (size_t)(chunk & 3)) * 1024
           + (size_t)(row & 127) * 8;
}

__device__ __forceinline__ void gload16(const void* g, void* l) {
    __builtin_amdgcn_global_load_lds(
        (const __attribute__((address_space(1))) unsigned int*)g,
        (__attribute__((address_space(3))) unsigned int*)l, 16, 0, 0);
}

__device__ __forceinline__ f32x4 mfma16(f16x8 a, f16x8 b, f32x4 c) {
    return __builtin_amdgcn_mfma_f32_16x16x32_f16(a, b, c, 0, 0, 0);
}

__device__ __forceinline__ unsigned short f2bf(float x) {
    unsigned int u = __float_as_uint(x);
    return (unsigned short)((u + 0x7fffu + ((u >> 16) & 1u)) >> 16);
}
__device__ __forceinline__ float bf2f(unsigned short u) {
    return __uint_as_float(((unsigned int)u) << 16);
}

__global__ __launch_bounds__(256) void k_zero(float* __restrict__ p, int n) {
    int i = blockIdx.x * 256 + threadIdx.x;
    if (i < n) p[i] = 0.0f;
}

// ---- normalize z rows (halves independently); coalesced tiled writes ----
__global__ __launch_bounds__(1024) void k_norm_z(const float* __restrict__ z,
        _Float16* __restrict__ zh, _Float16* __restrict__ zl,
        float* __restrict__ z2t, float* __restrict__ z2g) {
    int t = threadIdx.x;
    int r8 = t & 7, ck = t >> 3;              // row-in-8, chunk 0..127
    int row = blockIdx.x * 8 + r8;
    const float* src = z + (size_t)row * 1024 + (size_t)ck * 8;
    float4 v0 = *(const float4*)src;
    float4 v1 = *(const float4*)(src + 4);
    float v[8] = {v0.x,v0.y,v0.z,v0.w,v1.x,v1.y,v1.z,v1.w};
    float ss = 0.f;
#pragma unroll
    for (int e = 0; e < 8; ++e) ss += v[e]*v[e];
    __shared__ float red[8*132];
    int ri = r8*132 + ck;
    red[ri] = ss; __syncthreads();
    for (int s = 32; s > 0; s >>= 1) { if ((ck & 63) < s) red[ri] += red[ri+s]; __syncthreads(); }
    float nrm = sqrtf(red[r8*132 + (ck & 64)]);
    float nv[8]; float s2 = 0.f;
#pragma unroll
    for (int e = 0; e < 8; ++e) { nv[e] = v[e]/nrm; s2 += nv[e]*nv[e]; }
    __syncthreads();
    red[ri] = s2; __syncthreads();
    for (int s = 32; s > 0; s >>= 1) { if ((ck & 63) < s) red[ri] += red[ri+s]; __syncthreads(); }
    if ((ck & 63) == 0) { if (ck & 64) z2g[row] = red[ri]; else z2t[row] = red[ri]; }
    f16x8 h8, l8;
#pragma unroll
    for (int e = 0; e < 8; ++e) {
        float xs = nv[e]*SCL_H;
        _Float16 h = (_Float16)xs; h8[e] = h;
        l8[e] = (_Float16)((xs - (float)h) * 4096.0f);
    }
    size_t off = tiled_off(row, ck);
    *(f16x8*)(zh + off) = h8;
    *(f16x8*)(zl + off) = l8;
}

// ---- normalize emb rows (text ck<64, graph ck>=64) ----
__global__ __launch_bounds__(1024) void k_norm_e(const float* __restrict__ et, const float* __restrict__ eg,
        _Float16* __restrict__ eh, _Float16* __restrict__ el,
        float* __restrict__ e2t, float* __restrict__ e2g) {
    int t = threadIdx.x;
    int r8 = t & 7, ck = t >> 3;
    int row = blockIdx.x * 8 + r8;
    const float* src = (ck < 64) ? (et + (size_t)row * 512 + (size_t)ck * 8)
                                 : (eg + (size_t)row * 512 + (size_t)(ck - 64) * 8);
    float4 v0 = *(const float4*)src;
    float4 v1 = *(const float4*)(src + 4);
    float v[8] = {v0.x,v0.y,v0.z,v0.w,v1.x,v1.y,v1.z,v1.w};
    float ss = 0.f;
#pragma unroll
    for (int e = 0; e < 8; ++e) ss += v[e]*v[e];
    __shared__ float red[8*132];
    int ri = r8*132 + ck;
    red[ri] = ss; __syncthreads();
    for (int s = 32; s > 0; s >>= 1) { if ((ck & 63) < s) red[ri] += red[ri+s]; __syncthreads(); }
    float nrm = sqrtf(red[r8*132 + (ck & 64)]);
    float nv[8]; float s2 = 0.f;
#pragma unroll
    for (int e = 0; e < 8; ++e) { nv[e] = v[e]/nrm; s2 += nv[e]*nv[e]; }
    __syncthreads();
    red[ri] = s2; __syncthreads();
    for (int s = 32; s > 0; s >>= 1) { if ((ck & 63) < s) red[ri] += red[ri+s]; __syncthreads(); }
    if ((ck & 63) == 0) { if (ck & 64) e2g[row] = red[ri]; else e2t[row] = red[ri]; }
    f16x8 h8, l8;
#pragma unroll
    for (int e = 0; e < 8; ++e) {
        float xs = nv[e]*SCL_H;
        _Float16 h = (_Float16)xs; h8[e] = h;
        l8[e] = (_Float16)((xs - (float)h) * 4096.0f);
    }
    size_t off = tiled_off(row, ck);
    *(f16x8*)(eh + off) = h8;
    *(f16x8*)(el + off) = l8;
}

// ---- MFMA distance GEMM: 128x128 tile, 8 waves 2x4, 3-buffer counted-vmcnt pipeline ----
template<int PASS, bool STOREQ>
__global__ __launch_bounds__(512, 2) void k_gemm(
    const _Float16* __restrict__ zht, const _Float16* __restrict__ zlt,
    const _Float16* __restrict__ eht, const _Float16* __restrict__ elt,
    const float* __restrict__ z2t, const float* __restrict__ z2g,
    const float* __restrict__ e2t, const float* __restrict__ e2g,
    float* __restrict__ pm, float* __restrict__ pz, float* __restrict__ ps1,
    float* __restrict__ pdm, float* __restrict__ pdt, float* __restrict__ pdg,
    int* __restrict__ pix, unsigned short* __restrict__ qm,
    const float* __restrict__ lse, float* __restrict__ avgp)
{
    const int nj = blockIdx.x, bi = blockIdx.y;
    const int t = threadIdx.x;
    const int lane = t & 63, wid = t >> 6;
    const int wave_r = wid >> 2, wave_c = wid & 3;
    const int jf = lane & 15, g = lane >> 4;

    __shared__ __align__(16) _Float16 stg[4][3][4096];   // Ah, Al, Bh, Bl — 96KB
    __shared__ float sM[128][4], sDt[128][4], sDg[128][4], sDm[128][4], sZ[128][4], sS1[128][4];
    __shared__ int   sIx[128][4];
    __shared__ float sMf[128];
    __shared__ float scol[128];

    if (PASS == 2 && t < 128) scol[t] = 0.f;

    f32x4 acct[4][2] = {};
    f32x4 accg[4][2] = {};
    f32x4 accx[4][2] = {};

    const _Float16* pa_h = zht + (size_t)bi * 131072 + (size_t)t * 8;
    const _Float16* pa_l = zlt + (size_t)bi * 131072 + (size_t)t * 8;
    const _Float16* pb_h = eht + (size_t)nj * 131072 + (size_t)t * 8;
    const _Float16* pb_l = elt + (size_t)nj * 131072 + (size_t)t * 8;

#define STAGE(KT, B) { \
        gload16(pa_h + (size_t)(KT) * 4096, &stg[0][B][t * 8]); \
        gload16(pa_l + (size_t)(KT) * 4096, &stg[1][B][t * 8]); \
        gload16(pb_h + (size_t)(KT) * 4096, &stg[2][B][t * 8]); \
        gload16(pb_l + (size_t)(KT) * 4096, &stg[3][B][t * 8]); }

    STAGE(0, 0)
    STAGE(1, 1)
    int cb = 0;
    for (int kt = 0; kt < 32; ++kt) {
        asm volatile("s_waitcnt lgkmcnt(0)" ::: "memory");
        if (kt == 31) { asm volatile("s_waitcnt vmcnt(0)" ::: "memory"); }
        else          { asm volatile("s_waitcnt vmcnt(4)" ::: "memory"); }
        __builtin_amdgcn_s_barrier();
        __builtin_amdgcn_sched_barrier(0);
        if (kt < 30) {
            int sb = cb + 2; if (sb >= 3) sb -= 3;
            STAGE(kt + 2, sb)
        }
        f16x8 ah[4], al[4], bh[2], bl[2];
#pragma unroll
        for (int fr = 0; fr < 4; ++fr) {
            int off = g * 1024 + (wave_r * 64 + fr * 16 + jf) * 8;
            ah[fr] = *(const f16x8*)&stg[0][cb][off];
            al[fr] = *(const f16x8*)&stg[1][cb][off];
        }
#pragma unroll
        for (int fc = 0; fc < 2; ++fc) {
            int off = g * 1024 + (wave_c * 32 + fc * 16 + jf) * 8;
            bh[fc] = *(const f16x8*)&stg[2][cb][off];
            bl[fc] = *(const f16x8*)&stg[3][cb][off];
        }
        if (kt < 16) {
#pragma unroll
            for (int fr = 0; fr < 4; ++fr)
#pragma unroll
            for (int fc = 0; fc < 2; ++fc) {
                acct[fr][fc] = mfma16(ah[fr], bh[fc], acct[fr][fc]);
                accx[fr][fc] = mfma16(ah[fr], bl[fc], accx[fr][fc]);
                accx[fr][fc] = mfma16(al[fr], bh[fc], accx[fr][fc]);
            }
        } else {
#pragma unroll
            for (int fr = 0; fr < 4; ++fr)
#pragma unroll
            for (int fc = 0; fc < 2; ++fc) {
                accg[fr][fc] = mfma16(ah[fr], bh[fc], accg[fr][fc]);
                accx[fr][fc] = mfma16(ah[fr], bl[fc], accx[fr][fc]);
                accx[fr][fc] = mfma16(al[fr], bh[fc], accx[fr][fc]);
            }
        }
        cb = (cb == 2) ? 0 : cb + 1;
    }
#undef STAGE

    const int colbase = nj * 128 + wave_c * 32;
    float e2tc[2], e2gc[2];
#pragma unroll
    for (int fc = 0; fc < 2; ++fc) {
        e2tc[fc] = e2t[colbase + fc * 16 + jf];
        e2gc[fc] = e2g[colbase + fc * 16 + jf];
    }

    if constexpr (PASS == 1) {
        unsigned short* sQ = (unsigned short*)stg;   // 32KB overlay, staging is dead now
        // stage 1: per-row max / dmin / dt2 / dg2 over this wave's 32 cols; keep l in acct
#pragma unroll
        for (int fr = 0; fr < 4; ++fr) {
#pragma unroll
            for (int reg = 0; reg < 4; ++reg) {
                int rl = wave_r * 64 + fr * 16 + g * 4 + reg;
                int i  = bi * 128 + rl;
                float z2ti = z2t[i], z2gi = z2g[i];
                float mrow = -3.0e38f, dmin = 3.0e38f, dt2 = 0.f, dg2 = 0.f;
                int dix = 0;
#pragma unroll
                for (int fc = 0; fc < 2; ++fc) {
                    float ht = acct[fr][fc][reg], hg = accg[fr][fc][reg], xx = accx[fr][fc][reg];
                    float dta = z2ti + e2tc[fc] - ht * (2.0f * INV_HH);
                    float dga = z2gi + e2gc[fc] - hg * (2.0f * INV_HH);
                    float d   = (z2ti + z2gi) + (e2tc[fc] + e2gc[fc])
                              - 2.0f * INV_HH * (ht + hg + xx * (1.0f / 4096.0f));
                    float lv  = -100.0f * d;
                    acct[fr][fc][reg] = lv;
                    dt2 += dta * dta; dg2 += dga * dga;
                    int j = colbase + fc * 16 + jf;
                    if (d < dmin) { dmin = d; dix = j; }
                    mrow = fmaxf(mrow, lv);
                }
#pragma unroll
                for (int s = 1; s < 16; s <<= 1) {
                    mrow = fmaxf(mrow, __shfl_xor(mrow, s));
                    dt2 += __shfl_xor(dt2, s);
                    dg2 += __shfl_xor(dg2, s);
                    float ov = __shfl_xor(dmin, s); int oi = __shfl_xor(dix, s);
                    if (ov < dmin || (ov == dmin && oi < dix)) { dmin = ov; dix = oi; }
                }
                if (jf == 0) {
                    sM[rl][wave_c] = mrow; sDt[rl][wave_c] = dt2; sDg[rl][wave_c] = dg2;
                    sDm[rl][wave_c] = dmin; sIx[rl][wave_c] = dix;
                }
            }
        }
        __syncthreads();
        if (t < 128) sMf[t] = fmaxf(fmaxf(sM[t][0], sM[t][1]), fmaxf(sM[t][2], sM[t][3]));
        __syncthreads();
        // stage 2: Z, S1 vs block max; q into LDS
#pragma unroll
        for (int fr = 0; fr < 4; ++fr) {
#pragma unroll
            for (int reg = 0; reg < 4; ++reg) {
                int rl = wave_r * 64 + fr * 16 + g * 4 + reg;
                float M = sMf[rl];
                float Z = 0.f, S1 = 0.f;
#pragma unroll
                for (int fc = 0; fc < 2; ++fc) {
                    float lv = acct[fr][fc][reg];
                    float e  = expf(lv - M);
                    Z += e; S1 += e * lv;
                    if constexpr (STOREQ) sQ[rl * 128 + wave_c * 32 + fc * 16 + jf] = f2bf(e);
                }
#pragma unroll
                for (int s = 1; s < 16; s <<= 1) {
                    Z  += __shfl_xor(Z, s);
                    S1 += __shfl_xor(S1, s);
                }
                if (jf == 0) { sZ[rl][wave_c] = Z; sS1[rl][wave_c] = S1; }
            }
        }
        __syncthreads();
        if (t < 128) {
            float M = sMf[t];
            float Z = sZ[t][0] + sZ[t][1] + sZ[t][2] + sZ[t][3];
            float S1 = sS1[t][0] + sS1[t][1] + sS1[t][2] + sS1[t][3];
            float dt2 = sDt[t][0] + sDt[t][1] + sDt[t][2] + sDt[t][3];
            float dg2 = sDg[t][0] + sDg[t][1] + sDg[t][2] + sDg[t][3];
            float dmin = sDm[t][0]; int dix = sIx[t][0];
#pragma unroll
            for (int w = 1; w < 4; ++w) {
                float ov = sDm[t][w]; int oi = sIx[t][w];
                if (ov < dmin || (ov == dmin && oi < dix)) { dmin = ov; dix = oi; }
            }
            size_t pb = (size_t)(bi * 128 + t) * 64 + nj;
            pm[pb] = M; pz[pb] = Z; ps1[pb] = S1;
            pdm[pb] = dmin; pdt[pb] = dt2; pdg[pb] = dg2; pix[pb] = dix;
        }
        if constexpr (STOREQ) {
            // coalesced qm write: 128 rows x 256B
#pragma unroll
            for (int p = 0; p < 2; ++p) {
                int idx = p * 512 + t;
                int row = idx >> 3, seg = idx & 7;
                const uint4* s4 = (const uint4*)(sQ + row * 128 + seg * 16);
                uint4 q0 = s4[0], q1 = s4[1];
                uint4* d4 = (uint4*)(qm + (size_t)(bi * 128 + row) * 8192 + nj * 128 + seg * 16);
                d4[0] = q0; d4[1] = q1;
            }
        }
    } else {
        // PASS 2 fallback: recompute p = exp(l - lse), column sums
        float cs0 = 0.f, cs1 = 0.f;
#pragma unroll
        for (int fr = 0; fr < 4; ++fr) {
#pragma unroll
            for (int reg = 0; reg < 4; ++reg) {
                int rl = wave_r * 64 + fr * 16 + g * 4 + reg;
                int i  = bi * 128 + rl;
                float z2ti = z2t[i], z2gi = z2g[i];
                float lsei = lse[i];
#pragma unroll
                for (int fc = 0; fc < 2; ++fc) {
                    float ht = acct[fr][fc][reg], hg = accg[fr][fc][reg], xx = accx[fr][fc][reg];
                    float d = (z2ti + z2gi) + (e2tc[fc] + e2gc[fc])
                            - 2.0f * INV_HH * (ht + hg + xx * (1.0f / 4096.0f));
                    float lv = -100.0f * d;
                    float p = expf(lv - lsei);
                    if (fc == 0) cs0 += p; else cs1 += p;
                }
            }
        }
        cs0 += __shfl_xor(cs0, 16); cs0 += __shfl_xor(cs0, 32);
        cs1 += __shfl_xor(cs1, 16); cs1 += __shfl_xor(cs1, 32);
        if (g == 0) {
            atomicAdd(&scol[wave_c * 32 + jf], cs0);
            atomicAdd(&scol[wave_c * 32 + 16 + jf], cs1);
        }
        __syncthreads();
        if (t < 128) atomicAdd(&avgp[nj * 128 + t], scol[t]);
    }
}

// ---- merge 64 per-colblock partials per row; write pscale; NO global atomics ----
__global__ __launch_bounds__(256) void k_rowreduce(
    const float* __restrict__ pm, const float* __restrict__ pz, const float* __restrict__ ps1,
    const float* __restrict__ pdm, const float* __restrict__ pdt, const float* __restrict__ pdg,
    const int* __restrict__ pix,
    float* __restrict__ pscale, float* __restrict__ lse, int* __restrict__ idxo,
    float* __restrict__ rent, float* __restrict__ rdt, float* __restrict__ rdg,
    float* __restrict__ out)
{
    int b = blockIdx.x * 4 + (threadIdx.x >> 6);
    int l = threadIdx.x & 63;
    size_t pb = (size_t)b * 64 + l;
    float m0 = pm[pb];
    float m = m0;
#pragma unroll
    for (int s = 1; s < 64; s <<= 1) m = fmaxf(m, __shfl_xor(m, s));
    float sc = expf(m0 - m);
    float Z = pz[pb] * sc, S1 = ps1[pb] * sc;
    float dt2 = pdt[pb], dg2 = pdg[pb];
    float dmin = pdm[pb]; int dix = pix[pb];
#pragma unroll
    for (int s = 1; s < 64; s <<= 1) {
        Z += __shfl_xor(Z, s); S1 += __shfl_xor(S1, s);
        dt2 += __shfl_xor(dt2, s); dg2 += __shfl_xor(dg2, s);
        float ov = __shfl_xor(dmin, s); int oi = __shfl_xor(dix, s);
        if (ov < dmin || (ov == dmin && oi < dix)) { dmin = ov; dix = oi; }
    }
    float lseb = m + logf(Z);
    pscale[pb] = expf(m0 - lseb);
    if (l == 0) {
        lse[b] = lseb; idxo[b] = dix;
        out[O_IX + b] = (float)dix;
        rent[b] = lseb - S1 / Z;
        rdt[b] = dt2; rdg[b] = dg2;
    }
}

// ---- stored-q column sums, atomic-free: avg4[rb][n] = sum over 1024 rows ----
__global__ __launch_bounds__(256) void k_colsum(const unsigned short* __restrict__ qm,
                                                const float* __restrict__ pscale,
                                                float* __restrict__ avg4) {
    int cc = blockIdx.x, rb = blockIdx.y, t = threadIdx.x;
    int cp = t & 63, rg = t >> 6;
    float a0 = 0.f, a1 = 0.f;
    const unsigned short* qb = qm + (size_t)cc * 128 + (size_t)cp * 2;
#pragma unroll 4
    for (int rr = rg; rr < 1024; rr += 4) {
        int r = rb * 1024 + rr;
        float s = pscale[(size_t)r * 64 + cc];
        unsigned int q = *(const unsigned int*)(qb + (size_t)r * 8192);
        a0 += bf2f((unsigned short)(q & 0xffffu)) * s;
        a1 += bf2f((unsigned short)(q >> 16)) * s;
    }
    __shared__ float red[512];
    red[rg * 128 + cp * 2] = a0; red[rg * 128 + cp * 2 + 1] = a1;
    __syncthreads();
    if (rg == 0) {
        float s0 = red[cp*2]   + red[128+cp*2]   + red[256+cp*2]   + red[384+cp*2];
        float s1 = red[cp*2+1] + red[128+cp*2+1] + red[256+cp*2+1] + red[384+cp*2+1];
        avg4[(size_t)rb * 8192 + cc * 128 + cp * 2]     = s0;
        avg4[(size_t)rb * 8192 + cc * 128 + cp * 2 + 1] = s1;
    }
}

// ---- gather z_q outputs + per-row vq sums (no atomics) ----
__global__ __launch_bounds__(1024) void k_gather(
    const _Float16* __restrict__ zh, const _Float16* __restrict__ zl,
    const _Float16* __restrict__ eh, const _Float16* __restrict__ el,
    const int* __restrict__ idxi, float* __restrict__ out, float* __restrict__ gvq)
{
    int t = threadIdx.x;
    int r8 = t & 7, ck = t >> 3;
    int b = blockIdx.x * 8 + r8;
    int idx = idxi[b];
    size_t zo = tiled_off(b, ck), eo = tiled_off(idx, ck);
    f16x8 zh8 = *(const f16x8*)(zh + zo);
    f16x8 zl8 = *(const f16x8*)(zl + zo);
    f16x8 eh8 = *(const f16x8*)(eh + eo);
    f16x8 el8 = *(const f16x8*)(el + eo);
    float ss = 0.f; float oz[8], zq[8];
#pragma unroll
    for (int e = 0; e < 8; ++e) {
        float zn = ((float)zh8[e] + (float)zl8[e] * (1.0f / 4096.0f)) * (1.0f / SCL_H);
        float eq = ((float)eh8[e] + (float)el8[e] * (1.0f / 4096.0f)) * (1.0f / SCL_H);
        float df = eq - zn;
        zq[e] = eq; oz[e] = zn + df; ss += df * df;
    }
    float* dst = out + (size_t)b * 1024 + (size_t)ck * 8;
    *(float4*)dst       = make_float4(oz[0], oz[1], oz[2], oz[3]);
    *(float4*)(dst + 4) = make_float4(oz[4], oz[5], oz[6], oz[7]);
    float* tg = (ck < 64) ? (out + O_ZT + (size_t)b * 512 + (size_t)ck * 8)
                          : (out + O_ZG + (size_t)b * 512 + (size_t)(ck - 64) * 8);
    *(float4*)tg       = make_float4(zq[0], zq[1], zq[2], zq[3]);
    *(float4*)(tg + 4) = make_float4(zq[4], zq[5], zq[6], zq[7]);
    __shared__ float red[8*132];
    int ri = r8 * 132 + ck;
    red[ri] = ss; __syncthreads();
    for (int s = 64; s > 0; s >>= 1) { if (ck < s) red[ri] += red[ri + s]; __syncthreads(); }
    if (ck == 0) gvq[b] = red[ri];
}

__global__ __launch_bounds__(256) void k_finalize(const float* __restrict__ avg4,
        const float* __restrict__ rent, const float* __restrict__ rdt,
        const float* __restrict__ rdg, const float* __restrict__ gvq,
        float* __restrict__ out) {
    int t = threadIdx.x;
    float ent = 0.f, se = 0.f, dt = 0.f, dg = 0.f, vq = 0.f;
    for (int n = t; n < 8192; n += 256) {
        float a = 0.f;
#pragma unroll
        for (int k = 0; k < 8; ++k) a += avg4[(size_t)k * 8192 + n];
        a *= (1.0f / 8192.0f);
        ent -= a * logf(a + 1e-5f);
        se += rent[n]; dt += rdt[n]; dg += rdg[n]; vq += gvq[n];
    }
    __shared__ float red[256];
#define RED(x) { red[t] = x; __syncthreads(); \
    for (int s = 128; s > 0; s >>= 1) { if (t < s) red[t] += red[t + s]; __syncthreads(); } \
    x = red[0]; __syncthreads(); }
    RED(ent) RED(se) RED(dt) RED(dg) RED(vq)
#undef RED
    if (t == 0) {
        float vqm = vq * (1.0f / 8388608.0f);
        out[O_VQ]  = vqm;
        out[O_CM]  = 0.25f * vqm;
        out[O_ENT] = 0.1f * (se * (1.0f / 8192.0f) - ent);
        out[O_TD]  = dt * (1.0f / 8192.0f);
        out[O_GD]  = dg * (1.0f / 8192.0f);
    }
}

extern "C" void kernel_launch(void* const* d_in, const int* in_sizes, int n_in,
                              void* d_out, int out_size, void* d_ws, size_t ws_size,
                              hipStream_t stream) {
    const float* z  = (const float*)d_in[0];
    const float* et = (const float*)d_in[1];
    const float* eg = (const float*)d_in[2];
    float* out = (float*)d_out;
    float* ws  = (float*)d_ws;

    _Float16* zh = (_Float16*)(ws + WS_ZH);
    _Float16* zl = (_Float16*)(ws + WS_ZL);
    _Float16* eh = (_Float16*)(ws + WS_EH);
    _Float16* el = (_Float16*)(ws + WS_EL);
    float* z2t = ws + WS_Z2T;
    float* z2g = ws + WS_Z2G;
    float* e2t = ws + WS_E2T;
    float* e2g = ws + WS_E2G;
    float* pm  = ws + WS_PM;
    float* pz  = ws + WS_PZ;
    float* ps1 = ws + WS_PS1;
    float* pdm = ws + WS_PDM;
    float* pdt = ws + WS_PDT;
    float* pdg = ws + WS_PDG;
    int*   pix = (int*)(ws + WS_PIX);
    float* psc = ws + WS_PSC;
    float* lsep = ws + WS_LSE;
    int*   idxi = (int*)(ws + WS_IDX);
    float* rent = ws + WS_RENT;
    float* rdt  = ws + WS_RDT;
    float* rdg  = ws + WS_RDG;
    float* gvq  = ws + WS_GVQ;
    float* avg4 = ws + WS_AVG4;
    unsigned short* qm = (unsigned short*)(ws + WS_QM);

    bool storeq = (ws_size >= WS_STORE_END * sizeof(float));

    k_norm_z<<<1024, 1024, 0, stream>>>(z, zh, zl, z2t, z2g);
    k_norm_e<<<1024, 1024, 0, stream>>>(et, eg, eh, el, e2t, e2g);

    dim3 gg(64, 64);
    if (storeq) {
        k_gemm<1, true><<<gg, 512, 0, stream>>>(zh, zl, eh, el, z2t, z2g, e2t, e2g,
                                                pm, pz, ps1, pdm, pdt, pdg, pix, qm, lsep, avg4);
    } else {
        k_gemm<1, false><<<gg, 512, 0, stream>>>(zh, zl, eh, el, z2t, z2g, e2t, e2g,
                                                 pm, pz, ps1, pdm, pdt, pdg, pix, qm, lsep, avg4);
    }
    k_rowreduce<<<2048, 256, 0, stream>>>(pm, pz, ps1, pdm, pdt, pdg, pix,
                                          psc, lsep, idxi, rent, rdt, rdg, out);
    if (storeq) {
        k_colsum<<<dim3(64, 8), 256, 0, stream>>>(qm, psc, avg4);
    } else {
        k_zero<<<256, 256, 0, stream>>>(avg4, 65536);
        k_gemm<2, false><<<gg, 512, 0, stream>>>(zh, zl, eh, el, z2t, z2g, e2t, e2g,
                                                 pm, pz, ps1, pdm, pdt, pdg, pix, qm, lsep, avg4);
    }
    k_gather<<<1024, 1024, 0, stream>>>(zh, zl, eh, el, idxi, out, gvq);
    k_finalize<<<1, 256, 0, stream>>>(avg4, rent, rdt, rdg, gvq, out);
}

// Round 6
// 801.323 us; speedup vs baseline: 1.1143x; 1.1143x over previous
//
#include <hip/hip_runtime.h>
#include <cmath>

using f32x4 = __attribute__((ext_vector_type(4))) float;
using f16x8 = __attribute__((ext_vector_type(8))) _Float16;

#define SCL_H  256.0f
#define INV_HH (1.0f/65536.0f)

// ---------------- workspace layout (float units) ----------------
#define WS_ZH   ((size_t)0)
#define WS_ZL   ((size_t)4194304)
#define WS_EH   ((size_t)8388608)
#define WS_EL   ((size_t)12582912)
#define WS_Z2T  ((size_t)16777216)
#define WS_Z2G  ((size_t)16785408)
#define WS_E2T  ((size_t)16793600)
#define WS_E2G  ((size_t)16801792)
#define WS_PM   ((size_t)16809984)
#define WS_PZ   ((size_t)17334272)
#define WS_PS1  ((size_t)17858560)
#define WS_PDT  ((size_t)18382848)
#define WS_PDG  ((size_t)18907136)
#define WS_PD1  ((size_t)19431424)
#define WS_PD2  ((size_t)19955712)
#define WS_PI1  ((size_t)20480000)
#define WS_PI2  ((size_t)21004288)
#define WS_PSC  ((size_t)21528576)
#define WS_LSE  ((size_t)22052864)
#define WS_IDX  ((size_t)22061056)
#define WS_RENT ((size_t)22069248)
#define WS_RDT  ((size_t)22077440)
#define WS_RDG  ((size_t)22085632)
#define WS_GVQ  ((size_t)22093824)
#define WS_AVG4 ((size_t)22102016)
#define WS_QM   ((size_t)22167552)
#define WS_STORE_END ((size_t)55721984)

// ---------------- output layout (floats) ----------------
#define O_VQ  ((size_t)8388608)
#define O_CM  ((size_t)8388609)
#define O_ENT ((size_t)8388610)
#define O_TD  ((size_t)8388611)
#define O_GD  ((size_t)8388612)
#define O_ZT  ((size_t)8388613)
#define O_ZG  ((size_t)12582917)
#define O_IX  ((size_t)16777221)

__device__ __forceinline__ size_t tiled_off(int row, int chunk) {
    // chunk = k/8 in [0,128). layout: [rowblk][kt][slot][row&127][8]
    return (((size_t)(row >> 7) * 32 + (chunk >> 2)) * 4 + (size_t)(chunk & 3)) * 1024
           + (size_t)(row & 127) * 8;
}

__device__ __forceinline__ void gload16(const void* g, void* l) {
    __builtin_amdgcn_global_load_lds(
        (const __attribute__((address_space(1))) unsigned int*)g,
        (__attribute__((address_space(3))) unsigned int*)l, 16, 0, 0);
}

__device__ __forceinline__ f32x4 mfma16(f16x8 a, f16x8 b, f32x4 c) {
    return __builtin_amdgcn_mfma_f32_16x16x32_f16(a, b, c, 0, 0, 0);
}

__device__ __forceinline__ unsigned short f2bf(float x) {
    unsigned int u = __float_as_uint(x);
    return (unsigned short)((u + 0x7fffu + ((u >> 16) & 1u)) >> 16);
}
__device__ __forceinline__ float bf2f(unsigned short u) {
    return __uint_as_float(((unsigned int)u) << 16);
}

__device__ __forceinline__ bool dless(float a, int ia, float b, int ib) {
    return a < b || (a == b && ia < ib);
}
__device__ __forceinline__ void top2_point(float& d1, int& i1, float& d2, int& i2,
                                           float d, int j) {
    if (dless(d, j, d1, i1)) { d2 = d1; i2 = i1; d1 = d; i1 = j; }
    else if (dless(d, j, d2, i2)) { d2 = d; i2 = j; }
}
__device__ __forceinline__ void top2_merge(float& d1, int& i1, float& d2, int& i2,
                                           float od1, int oi1, float od2, int oi2) {
    if (dless(od1, oi1, d1, i1)) {
        float nd2; int ni2;
        if (dless(d1, i1, od2, oi2)) { nd2 = d1; ni2 = i1; } else { nd2 = od2; ni2 = oi2; }
        d1 = od1; i1 = oi1; d2 = nd2; i2 = ni2;
    } else if (dless(od1, oi1, d2, i2)) {
        d2 = od1; i2 = oi1;
    }
}

__global__ __launch_bounds__(256) void k_zero(float* __restrict__ p, int n) {
    int i = blockIdx.x * 256 + threadIdx.x;
    if (i < n) p[i] = 0.0f;
}

// ---- normalize z rows (halves independently); tiled fp16 hi/lo + sq-sums ----
__global__ __launch_bounds__(1024) void k_norm_z(const float* __restrict__ z,
        _Float16* __restrict__ zh, _Float16* __restrict__ zl,
        float* __restrict__ z2t, float* __restrict__ z2g) {
    int t = threadIdx.x;
    int r8 = t & 7, ck = t >> 3;
    int row = blockIdx.x * 8 + r8;
    const float* src = z + (size_t)row * 1024 + (size_t)ck * 8;
    float4 v0 = *(const float4*)src;
    float4 v1 = *(const float4*)(src + 4);
    float v[8] = {v0.x,v0.y,v0.z,v0.w,v1.x,v1.y,v1.z,v1.w};
    float ss = 0.f;
#pragma unroll
    for (int e = 0; e < 8; ++e) ss += v[e]*v[e];
    __shared__ float red[8*132];
    int ri = r8*132 + ck;
    red[ri] = ss; __syncthreads();
    for (int s = 32; s > 0; s >>= 1) { if ((ck & 63) < s) red[ri] += red[ri+s]; __syncthreads(); }
    float nrm = sqrtf(red[r8*132 + (ck & 64)]);
    float nv[8]; float s2 = 0.f;
#pragma unroll
    for (int e = 0; e < 8; ++e) { nv[e] = v[e]/nrm; s2 += nv[e]*nv[e]; }
    __syncthreads();
    red[ri] = s2; __syncthreads();
    for (int s = 32; s > 0; s >>= 1) { if ((ck & 63) < s) red[ri] += red[ri+s]; __syncthreads(); }
    if ((ck & 63) == 0) { if (ck & 64) z2g[row] = red[ri]; else z2t[row] = red[ri]; }
    f16x8 h8, l8;
#pragma unroll
    for (int e = 0; e < 8; ++e) {
        float xs = nv[e]*SCL_H;
        _Float16 h = (_Float16)xs; h8[e] = h;
        l8[e] = (_Float16)((xs - (float)h) * 4096.0f);
    }
    size_t off = tiled_off(row, ck);
    *(f16x8*)(zh + off) = h8;
    *(f16x8*)(zl + off) = l8;
}

// ---- normalize emb rows (text ck<64, graph ck>=64) ----
__global__ __launch_bounds__(1024) void k_norm_e(const float* __restrict__ et, const float* __restrict__ eg,
        _Float16* __restrict__ eh, _Float16* __restrict__ el,
        float* __restrict__ e2t, float* __restrict__ e2g) {
    int t = threadIdx.x;
    int r8 = t & 7, ck = t >> 3;
    int row = blockIdx.x * 8 + r8;
    const float* src = (ck < 64) ? (et + (size_t)row * 512 + (size_t)ck * 8)
                                 : (eg + (size_t)row * 512 + (size_t)(ck - 64) * 8);
    float4 v0 = *(const float4*)src;
    float4 v1 = *(const float4*)(src + 4);
    float v[8] = {v0.x,v0.y,v0.z,v0.w,v1.x,v1.y,v1.z,v1.w};
    float ss = 0.f;
#pragma unroll
    for (int e = 0; e < 8; ++e) ss += v[e]*v[e];
    __shared__ float red[8*132];
    int ri = r8*132 + ck;
    red[ri] = ss; __syncthreads();
    for (int s = 32; s > 0; s >>= 1) { if ((ck & 63) < s) red[ri] += red[ri+s]; __syncthreads(); }
    float nrm = sqrtf(red[r8*132 + (ck & 64)]);
    float nv[8]; float s2 = 0.f;
#pragma unroll
    for (int e = 0; e < 8; ++e) { nv[e] = v[e]/nrm; s2 += nv[e]*nv[e]; }
    __syncthreads();
    red[ri] = s2; __syncthreads();
    for (int s = 32; s > 0; s >>= 1) { if ((ck & 63) < s) red[ri] += red[ri+s]; __syncthreads(); }
    if ((ck & 63) == 0) { if (ck & 64) e2g[row] = red[ri]; else e2t[row] = red[ri]; }
    f16x8 h8, l8;
#pragma unroll
    for (int e = 0; e < 8; ++e) {
        float xs = nv[e]*SCL_H;
        _Float16 h = (_Float16)xs; h8[e] = h;
        l8[e] = (_Float16)((xs - (float)h) * 4096.0f);
    }
    size_t off = tiled_off(row, ck);
    *(f16x8*)(eh + off) = h8;
    *(f16x8*)(el + off) = l8;
}

// ---- hi-only MFMA distance GEMM: 128x128 tile, 8 waves 2x4, round-2 2-phase loop ----
template<int PASS, bool STOREQ>
__global__ __launch_bounds__(512, 2) void k_gemm(
    const _Float16* __restrict__ zht, const _Float16* __restrict__ eht,
    const float* __restrict__ z2t, const float* __restrict__ z2g,
    const float* __restrict__ e2t, const float* __restrict__ e2g,
    float* __restrict__ pm, float* __restrict__ pz, float* __restrict__ ps1,
    float* __restrict__ pdt, float* __restrict__ pdg,
    float* __restrict__ pd1, float* __restrict__ pd2,
    int* __restrict__ pi1, int* __restrict__ pi2,
    unsigned short* __restrict__ qm,
    const float* __restrict__ lse, float* __restrict__ avgp)
{
    const int nj = blockIdx.x, bi = blockIdx.y;
    const int t = threadIdx.x;
    const int lane = t & 63, wid = t >> 6;
    const int wave_r = wid >> 2, wave_c = wid & 3;
    const int jf = lane & 15, g = lane >> 4;

    __shared__ __align__(16) _Float16 stg[2][2][4096];   // [A/B][buf] — 32KB
    __shared__ float sM[128][4], sDt[128][4], sDg[128][4], sZ[128][4], sS1[128][4];
    __shared__ float sD1[128][4], sD2[128][4];
    __shared__ int   sI1[128][4], sI2[128][4];
    __shared__ float sMf[128];
    __shared__ float scol[128];

    if (PASS == 2 && t < 128) scol[t] = 0.f;

    f32x4 acct[4][2] = {};
    f32x4 accg[4][2] = {};

    const _Float16* pa = zht + (size_t)bi * 131072 + (size_t)t * 8;
    const _Float16* pb = eht + (size_t)nj * 131072 + (size_t)t * 8;

#define STAGE(KT, B) { \
        gload16(pa + (size_t)(KT) * 4096, &stg[0][B][t * 8]); \
        gload16(pb + (size_t)(KT) * 4096, &stg[1][B][t * 8]); }

    int cur = 0;
    STAGE(0, 0)
    asm volatile("s_waitcnt vmcnt(0)" ::: "memory");
    __syncthreads();

    for (int kt = 0; kt < 32; ++kt) {
        if (kt + 1 < 32) {
            if (cur == 0) STAGE(kt + 1, 1) else STAGE(kt + 1, 0)
        }
        f16x8 ah[4], bh[2];
#pragma unroll
        for (int fr = 0; fr < 4; ++fr) {
            int off = g * 1024 + (wave_r * 64 + fr * 16 + jf) * 8;
            ah[fr] = *(const f16x8*)&stg[0][cur][off];
        }
#pragma unroll
        for (int fc = 0; fc < 2; ++fc) {
            int off = g * 1024 + (wave_c * 32 + fc * 16 + jf) * 8;
            bh[fc] = *(const f16x8*)&stg[1][cur][off];
        }
        if (kt < 16) {
#pragma unroll
            for (int fr = 0; fr < 4; ++fr)
#pragma unroll
            for (int fc = 0; fc < 2; ++fc)
                acct[fr][fc] = mfma16(ah[fr], bh[fc], acct[fr][fc]);
        } else {
#pragma unroll
            for (int fr = 0; fr < 4; ++fr)
#pragma unroll
            for (int fc = 0; fc < 2; ++fc)
                accg[fr][fc] = mfma16(ah[fr], bh[fc], accg[fr][fc]);
        }
        asm volatile("s_waitcnt vmcnt(0)" ::: "memory");
        __syncthreads();
        cur ^= 1;
    }
#undef STAGE

    const int colbase = nj * 128 + wave_c * 32;
    float e2tc[2], e2gc[2];
#pragma unroll
    for (int fc = 0; fc < 2; ++fc) {
        e2tc[fc] = e2t[colbase + fc * 16 + jf];
        e2gc[fc] = e2g[colbase + fc * 16 + jf];
    }

    if constexpr (PASS == 1) {
        // stage 1: per-row max / top-2 / dt2 / dg2 over this wave's 32 cols; keep l in acct
#pragma unroll
        for (int fr = 0; fr < 4; ++fr) {
#pragma unroll
            for (int reg = 0; reg < 4; ++reg) {
                int rl = wave_r * 64 + fr * 16 + g * 4 + reg;
                int i  = bi * 128 + rl;
                float z2ti = z2t[i], z2gi = z2g[i];
                float mrow = -3.0e38f, dt2 = 0.f, dg2 = 0.f;
                float d1 = 3.0e38f, d2 = 3.0e38f;
                int i1 = 0x7fffffff, i2 = 0x7fffffff;
#pragma unroll
                for (int fc = 0; fc < 2; ++fc) {
                    float ht = acct[fr][fc][reg], hg = accg[fr][fc][reg];
                    float dta = z2ti + e2tc[fc] - ht * (2.0f * INV_HH);
                    float dga = z2gi + e2gc[fc] - hg * (2.0f * INV_HH);
                    float d   = dta + dga;
                    float lv  = -100.0f * d;
                    acct[fr][fc][reg] = lv;
                    dt2 += dta * dta; dg2 += dga * dga;
                    int j = colbase + fc * 16 + jf;
                    top2_point(d1, i1, d2, i2, d, j);
                    mrow = fmaxf(mrow, lv);
                }
#pragma unroll
                for (int s = 1; s < 16; s <<= 1) {
                    mrow = fmaxf(mrow, __shfl_xor(mrow, s));
                    dt2 += __shfl_xor(dt2, s);
                    dg2 += __shfl_xor(dg2, s);
                    float od1 = __shfl_xor(d1, s); int oi1 = __shfl_xor(i1, s);
                    float od2 = __shfl_xor(d2, s); int oi2 = __shfl_xor(i2, s);
                    top2_merge(d1, i1, d2, i2, od1, oi1, od2, oi2);
                }
                if (jf == 0) {
                    sM[rl][wave_c] = mrow; sDt[rl][wave_c] = dt2; sDg[rl][wave_c] = dg2;
                    sD1[rl][wave_c] = d1; sI1[rl][wave_c] = i1;
                    sD2[rl][wave_c] = d2; sI2[rl][wave_c] = i2;
                }
            }
        }
        __syncthreads();
        if (t < 128) sMf[t] = fmaxf(fmaxf(sM[t][0], sM[t][1]), fmaxf(sM[t][2], sM[t][3]));
        __syncthreads();
        // stage 2: Z, S1 vs block max; q store (direct, coalesced 32B per 16 lanes)
#pragma unroll
        for (int fr = 0; fr < 4; ++fr) {
#pragma unroll
            for (int reg = 0; reg < 4; ++reg) {
                int rl = wave_r * 64 + fr * 16 + g * 4 + reg;
                float M = sMf[rl];
                float Z = 0.f, S1 = 0.f;
#pragma unroll
                for (int fc = 0; fc < 2; ++fc) {
                    float lv = acct[fr][fc][reg];
                    float e  = expf(lv - M);
                    Z += e; S1 += e * lv;
                    if constexpr (STOREQ) {
                        size_t qo = (size_t)(bi * 128 + rl) * 8192 + (colbase + fc * 16 + jf);
                        qm[qo] = f2bf(e);
                    }
                }
#pragma unroll
                for (int s = 1; s < 16; s <<= 1) {
                    Z  += __shfl_xor(Z, s);
                    S1 += __shfl_xor(S1, s);
                }
                if (jf == 0) { sZ[rl][wave_c] = Z; sS1[rl][wave_c] = S1; }
            }
        }
        __syncthreads();
        if (t < 128) {
            float M = sMf[t];
            float Z = sZ[t][0] + sZ[t][1] + sZ[t][2] + sZ[t][3];
            float S1 = sS1[t][0] + sS1[t][1] + sS1[t][2] + sS1[t][3];
            float dt2 = sDt[t][0] + sDt[t][1] + sDt[t][2] + sDt[t][3];
            float dg2 = sDg[t][0] + sDg[t][1] + sDg[t][2] + sDg[t][3];
            float d1 = sD1[t][0], d2 = sD2[t][0];
            int i1 = sI1[t][0], i2 = sI2[t][0];
#pragma unroll
            for (int w = 1; w < 4; ++w)
                top2_merge(d1, i1, d2, i2, sD1[t][w], sI1[t][w], sD2[t][w], sI2[t][w]);
            size_t pb = (size_t)(bi * 128 + t) * 64 + nj;
            pm[pb] = M; pz[pb] = Z; ps1[pb] = S1;
            pdt[pb] = dt2; pdg[pb] = dg2;
            pd1[pb] = d1; pd2[pb] = d2; pi1[pb] = i1; pi2[pb] = i2;
        }
    } else {
        // PASS 2 fallback: recompute p = exp(l - lse), column sums
        float cs0 = 0.f, cs1 = 0.f;
#pragma unroll
        for (int fr = 0; fr < 4; ++fr) {
#pragma unroll
            for (int reg = 0; reg < 4; ++reg) {
                int rl = wave_r * 64 + fr * 16 + g * 4 + reg;
                int i  = bi * 128 + rl;
                float z2ti = z2t[i], z2gi = z2g[i];
                float lsei = lse[i];
#pragma unroll
                for (int fc = 0; fc < 2; ++fc) {
                    float ht = acct[fr][fc][reg], hg = accg[fr][fc][reg];
                    float d = (z2ti + z2gi) + (e2tc[fc] + e2gc[fc])
                            - 2.0f * INV_HH * (ht + hg);
                    float lv = -100.0f * d;
                    float p = expf(lv - lsei);
                    if (fc == 0) cs0 += p; else cs1 += p;
                }
            }
        }
        cs0 += __shfl_xor(cs0, 16); cs0 += __shfl_xor(cs0, 32);
        cs1 += __shfl_xor(cs1, 16); cs1 += __shfl_xor(cs1, 32);
        if (g == 0) {
            atomicAdd(&scol[wave_c * 32 + jf], cs0);
            atomicAdd(&scol[wave_c * 32 + 16 + jf], cs1);
        }
        __syncthreads();
        if (t < 128) atomicAdd(&avgp[nj * 128 + t], scol[t]);
    }
}

// ---- merge 64 per-colblock softmax partials per row; write pscale; no atomics ----
__global__ __launch_bounds__(256) void k_rowreduce(
    const float* __restrict__ pm, const float* __restrict__ pz, const float* __restrict__ ps1,
    const float* __restrict__ pdt, const float* __restrict__ pdg,
    float* __restrict__ pscale, float* __restrict__ lse,
    float* __restrict__ rent, float* __restrict__ rdt, float* __restrict__ rdg)
{
    int b = blockIdx.x * 4 + (threadIdx.x >> 6);
    int l = threadIdx.x & 63;
    size_t pb = (size_t)b * 64 + l;
    float m0 = pm[pb];
    float m = m0;
#pragma unroll
    for (int s = 1; s < 64; s <<= 1) m = fmaxf(m, __shfl_xor(m, s));
    float sc = expf(m0 - m);
    float Z = pz[pb] * sc, S1 = ps1[pb] * sc;
    float dt2 = pdt[pb], dg2 = pdg[pb];
#pragma unroll
    for (int s = 1; s < 64; s <<= 1) {
        Z += __shfl_xor(Z, s); S1 += __shfl_xor(S1, s);
        dt2 += __shfl_xor(dt2, s); dg2 += __shfl_xor(dg2, s);
    }
    float lseb = m + logf(Z);
    pscale[pb] = expf(m0 - lseb);
    if (l == 0) {
        lse[b] = lseb;
        rent[b] = lseb - S1 / Z;
        rdt[b] = dt2; rdg[b] = dg2;
    }
}

// ---- exact-argmin refinement from per-tile top-2 hi-only candidates ----
__global__ __launch_bounds__(256) void k_refine(
    const float* __restrict__ pd1, const float* __restrict__ pd2,
    const int* __restrict__ pi1, const int* __restrict__ pi2,
    const _Float16* __restrict__ zh, const _Float16* __restrict__ zl,
    const _Float16* __restrict__ eh, const _Float16* __restrict__ el,
    const float* __restrict__ z2t, const float* __restrict__ z2g,
    const float* __restrict__ e2t, const float* __restrict__ e2g,
    int* __restrict__ idxi, float* __restrict__ out)
{
    int row = blockIdx.x * 4 + (threadIdx.x >> 6);
    int l = threadIdx.x & 63;
    size_t base = (size_t)row * 64;
    float da = pd1[base + l]; int ja = pi1[base + l];
    float db = pd2[base + l]; int jb = pi2[base + l];
    float M = fminf(da, db);
#pragma unroll
    for (int s = 1; s < 64; s <<= 1) M = fminf(M, __shfl_xor(M, s));
    const float eps = 1.0e-3f;
    unsigned long long mA = __ballot(da <= M + eps);
    unsigned long long mB = __ballot(db <= M + eps);

    // preload this row's z chunks: lane l handles chunks 2l, 2l+1 (16 elems)
    float zv[16];
    {
        size_t o0 = tiled_off(row, 2 * l), o1 = tiled_off(row, 2 * l + 1);
        f16x8 h0 = *(const f16x8*)(zh + o0), l0 = *(const f16x8*)(zl + o0);
        f16x8 h1 = *(const f16x8*)(zh + o1), l1 = *(const f16x8*)(zl + o1);
#pragma unroll
        for (int e = 0; e < 8; ++e) {
            zv[e]     = (float)h0[e] * (1.0f/256.0f) + (float)l0[e] * (1.0f/1048576.0f);
            zv[8 + e] = (float)h1[e] * (1.0f/256.0f) + (float)l1[e] * (1.0f/1048576.0f);
        }
    }
    float zz = z2t[row] + z2g[row];
    float bd = 3.0e38f; int bj = 0x7fffffff;
    while (mA | mB) {
        int cand;
        if (mA) { int s = (int)__ffsll(mA) - 1; mA &= mA - 1; cand = __shfl(ja, s); }
        else    { int s = (int)__ffsll(mB) - 1; mB &= mB - 1; cand = __shfl(jb, s); }
        size_t o0 = tiled_off(cand, 2 * l), o1 = tiled_off(cand, 2 * l + 1);
        f16x8 h0 = *(const f16x8*)(eh + o0), l0 = *(const f16x8*)(el + o0);
        f16x8 h1 = *(const f16x8*)(eh + o1), l1 = *(const f16x8*)(el + o1);
        float dot = 0.f;
#pragma unroll
        for (int e = 0; e < 8; ++e) {
            float ev0 = (float)h0[e] * (1.0f/256.0f) + (float)l0[e] * (1.0f/1048576.0f);
            float ev1 = (float)h1[e] * (1.0f/256.0f) + (float)l1[e] * (1.0f/1048576.0f);
            dot += zv[e] * ev0 + zv[8 + e] * ev1;
        }
#pragma unroll
        for (int s = 1; s < 64; s <<= 1) dot += __shfl_xor(dot, s);
        float d = zz + e2t[cand] + e2g[cand] - 2.0f * dot;
        if (d < bd || (d == bd && cand < bj)) { bd = d; bj = cand; }
    }
    if (l == 0) { idxi[row] = bj; out[O_IX + row] = (float)bj; }
}

// ---- stored-q column sums, atomic-free ----
__global__ __launch_bounds__(256) void k_colsum(const unsigned short* __restrict__ qm,
                                                const float* __restrict__ pscale,
                                                float* __restrict__ avg4) {
    int cc = blockIdx.x, rb = blockIdx.y, t = threadIdx.x;
    int cp = t & 63, rg = t >> 6;
    float a0 = 0.f, a1 = 0.f;
    const unsigned short* qb = qm + (size_t)cc * 128 + (size_t)cp * 2;
#pragma unroll 4
    for (int rr = rg; rr < 1024; rr += 4) {
        int r = rb * 1024 + rr;
        float s = pscale[(size_t)r * 64 + cc];
        unsigned int q = *(const unsigned int*)(qb + (size_t)r * 8192);
        a0 += bf2f((unsigned short)(q & 0xffffu)) * s;
        a1 += bf2f((unsigned short)(q >> 16)) * s;
    }
    __shared__ float red[512];
    red[rg * 128 + cp * 2] = a0; red[rg * 128 + cp * 2 + 1] = a1;
    __syncthreads();
    if (rg == 0) {
        float s0 = red[cp*2]   + red[128+cp*2]   + red[256+cp*2]   + red[384+cp*2];
        float s1 = red[cp*2+1] + red[128+cp*2+1] + red[256+cp*2+1] + red[384+cp*2+1];
        avg4[(size_t)rb * 8192 + cc * 128 + cp * 2]     = s0;
        avg4[(size_t)rb * 8192 + cc * 128 + cp * 2 + 1] = s1;
    }
}

// ---- gather z_q outputs + per-row vq sums ----
__global__ __launch_bounds__(1024) void k_gather(
    const _Float16* __restrict__ zh, const _Float16* __restrict__ zl,
    const _Float16* __restrict__ eh, const _Float16* __restrict__ el,
    const int* __restrict__ idxi, float* __restrict__ out, float* __restrict__ gvq)
{
    int t = threadIdx.x;
    int r8 = t & 7, ck = t >> 3;
    int b = blockIdx.x * 8 + r8;
    int idx = idxi[b];
    size_t zo = tiled_off(b, ck), eo = tiled_off(idx, ck);
    f16x8 zh8 = *(const f16x8*)(zh + zo);
    f16x8 zl8 = *(const f16x8*)(zl + zo);
    f16x8 eh8 = *(const f16x8*)(eh + eo);
    f16x8 el8 = *(const f16x8*)(el + eo);
    float ss = 0.f; float oz[8], zq[8];
#pragma unroll
    for (int e = 0; e < 8; ++e) {
        float zn = ((float)zh8[e] + (float)zl8[e] * (1.0f / 4096.0f)) * (1.0f / SCL_H);
        float eq = ((float)eh8[e] + (float)el8[e] * (1.0f / 4096.0f)) * (1.0f / SCL_H);
        float df = eq - zn;
        zq[e] = eq; oz[e] = zn + df; ss += df * df;
    }
    float* dst = out + (size_t)b * 1024 + (size_t)ck * 8;
    *(float4*)dst       = make_float4(oz[0], oz[1], oz[2], oz[3]);
    *(float4*)(dst + 4) = make_float4(oz[4], oz[5], oz[6], oz[7]);
    float* tg = (ck < 64) ? (out + O_ZT + (size_t)b * 512 + (size_t)ck * 8)
                          : (out + O_ZG + (size_t)b * 512 + (size_t)(ck - 64) * 8);
    *(float4*)tg       = make_float4(zq[0], zq[1], zq[2], zq[3]);
    *(float4*)(tg + 4) = make_float4(zq[4], zq[5], zq[6], zq[7]);
    __shared__ float red[8*132];
    int ri = r8 * 132 + ck;
    red[ri] = ss; __syncthreads();
    for (int s = 64; s > 0; s >>= 1) { if (ck < s) red[ri] += red[ri + s]; __syncthreads(); }
    if (ck == 0) gvq[b] = red[ri];
}

__global__ __launch_bounds__(256) void k_finalize(const float* __restrict__ avg4,
        const float* __restrict__ rent, const float* __restrict__ rdt,
        const float* __restrict__ rdg, const float* __restrict__ gvq,
        float* __restrict__ out) {
    int t = threadIdx.x;
    float ent = 0.f, se = 0.f, dt = 0.f, dg = 0.f, vq = 0.f;
    for (int n = t; n < 8192; n += 256) {
        float a = 0.f;
#pragma unroll
        for (int k = 0; k < 8; ++k) a += avg4[(size_t)k * 8192 + n];
        a *= (1.0f / 8192.0f);
        ent -= a * logf(a + 1e-5f);
        se += rent[n]; dt += rdt[n]; dg += rdg[n]; vq += gvq[n];
    }
    __shared__ float red[256];
#define RED(x) { red[t] = x; __syncthreads(); \
    for (int s = 128; s > 0; s >>= 1) { if (t < s) red[t] += red[t + s]; __syncthreads(); } \
    x = red[0]; __syncthreads(); }
    RED(ent) RED(se) RED(dt) RED(dg) RED(vq)
#undef RED
    if (t == 0) {
        float vqm = vq * (1.0f / 8388608.0f);
        out[O_VQ]  = vqm;
        out[O_CM]  = 0.25f * vqm;
        out[O_ENT] = 0.1f * (se * (1.0f / 8192.0f) - ent);
        out[O_TD]  = dt * (1.0f / 8192.0f);
        out[O_GD]  = dg * (1.0f / 8192.0f);
    }
}

extern "C" void kernel_launch(void* const* d_in, const int* in_sizes, int n_in,
                              void* d_out, int out_size, void* d_ws, size_t ws_size,
                              hipStream_t stream) {
    const float* z  = (const float*)d_in[0];
    const float* et = (const float*)d_in[1];
    const float* eg = (const float*)d_in[2];
    float* out = (float*)d_out;
    float* ws  = (float*)d_ws;

    _Float16* zh = (_Float16*)(ws + WS_ZH);
    _Float16* zl = (_Float16*)(ws + WS_ZL);
    _Float16* eh = (_Float16*)(ws + WS_EH);
    _Float16* el = (_Float16*)(ws + WS_EL);
    float* z2t = ws + WS_Z2T;
    float* z2g = ws + WS_Z2G;
    float* e2t = ws + WS_E2T;
    float* e2g = ws + WS_E2G;
    float* pm  = ws + WS_PM;
    float* pz  = ws + WS_PZ;
    float* ps1 = ws + WS_PS1;
    float* pdt = ws + WS_PDT;
    float* pdg = ws + WS_PDG;
    float* pd1 = ws + WS_PD1;
    float* pd2 = ws + WS_PD2;
    int*   pi1 = (int*)(ws + WS_PI1);
    int*   pi2 = (int*)(ws + WS_PI2);
    float* psc = ws + WS_PSC;
    float* lsep = ws + WS_LSE;
    int*   idxi = (int*)(ws + WS_IDX);
    float* rent = ws + WS_RENT;
    float* rdt  = ws + WS_RDT;
    float* rdg  = ws + WS_RDG;
    float* gvq  = ws + WS_GVQ;
    float* avg4 = ws + WS_AVG4;
    unsigned short* qm = (unsigned short*)(ws + WS_QM);

    bool storeq = (ws_size >= WS_STORE_END * sizeof(float));

    k_norm_z<<<1024, 1024, 0, stream>>>(z, zh, zl, z2t, z2g);
    k_norm_e<<<1024, 1024, 0, stream>>>(et, eg, eh, el, e2t, e2g);

    dim3 gg(64, 64);
    if (storeq) {
        k_gemm<1, true><<<gg, 512, 0, stream>>>(zh, eh, z2t, z2g, e2t, e2g,
                                                pm, pz, ps1, pdt, pdg,
                                                pd1, pd2, pi1, pi2, qm, lsep, avg4);
    } else {
        k_gemm<1, false><<<gg, 512, 0, stream>>>(zh, eh, z2t, z2g, e2t, e2g,
                                                 pm, pz, ps1, pdt, pdg,
                                                 pd1, pd2, pi1, pi2, qm, lsep, avg4);
    }
    k_rowreduce<<<2048, 256, 0, stream>>>(pm, pz, ps1, pdt, pdg,
                                          psc, lsep, rent, rdt, rdg);
    k_refine<<<2048, 256, 0, stream>>>(pd1, pd2, pi1, pi2, zh, zl, eh, el,
                                       z2t, z2g, e2t, e2g, idxi, out);
    if (storeq) {
        k_colsum<<<dim3(64, 8), 256, 0, stream>>>(qm, psc, avg4);
    } else {
        k_zero<<<256, 256, 0, stream>>>(avg4, 65536);
        k_gemm<2, false><<<gg, 512, 0, stream>>>(zh, eh, z2t, z2g, e2t, e2g,
                                                 pm, pz, ps1, pdt, pdg,
                                                 pd1, pd2, pi1, pi2, qm, lsep, avg4);
    }
    k_gather<<<1024, 1024, 0, stream>>>(zh, zl, eh, el, idxi, out, gvq);
    k_finalize<<<1, 256, 0, stream>>>(avg4, rent, rdt, rdg, gvq, out);
}